// Round 5
// baseline (97.322 us; speedup 1.0000x reference)
//
#include <hip/hip_runtime.h>

#define NEXP 5
#define MAXF 128
#define NOUT 512
#define TPB  64
#define PITCH 136   // ushorts per LDS x-row (272 B stride)

typedef __attribute__((ext_vector_type(8))) short short8;
typedef __attribute__((ext_vector_type(4))) float floatx4;

__device__ __forceinline__ ushort f2bf(float f) {   // RNE fp32->bf16
    uint u = __float_as_uint(f);
    u += 0x7FFF + ((u >> 16) & 1);
    return (ushort)(u >> 16);
}

// wb bf16 [5][4][32][64][8]: frag order, idx = ((e*4+s)*32 + nb16)*64 + lane,
// elem j at k = s*32 + (lane>>4)*8 + j, n = nb16*16 + (lane&15); zero past K.
__global__ __launch_bounds__(256) void misl_pack(
    const float* __restrict__ w, ushort* __restrict__ wb) {
    const int idx = blockIdx.x * 256 + threadIdx.x;   // 0..40959
    const int lane = idx & 63, nb16 = (idx >> 6) & 31;
    const int s = (idx >> 11) & 3, e = idx >> 13;
    if (e < NEXP) {
        const int ncol = nb16 * 16 + (lane & 15);
        const int k0 = s * 32 + (lane >> 4) * 8;
        const int K = 8 << e;
        const float* wr = w + ((size_t)e * NOUT + ncol) * MAXF + k0;
        short8 v;
        #pragma unroll
        for (int j = 0; j < 8; ++j)
            v[j] = (short)((k0 + j < K) ? f2bf(wr[j]) : (ushort)0);
        *(short8*)(wb + (size_t)idx * 8) = v;
    }
}

// Swapped-operand MFMA: A = W frag (rows = out features), B = x frag (cols =
// tokens). D[n][tok]: lane holds 4 consecutive n per acc tile for its own
// token (lane&15) -> float4 nontemporal C-writes, float4 bias init, no shfl.
template <int E>
__device__ __forceinline__ void run_expert(
    const ushort* __restrict__ xs, const int* __restrict__ perm,
    const ushort* __restrict__ wb, const float* __restrict__ b,
    float* __restrict__ out, int t0, int boff, int c, int lane, int n_base) {
    constexpr int NS = (E == 4) ? 4 : (E == 3) ? 2 : 1;
    const int m = lane & 15, q = lane >> 4;
    const int nb16 = n_base >> 4;
    const ushort* wbe = wb + (size_t)E * 4 * 32 * 64 * 8;

    short8 wf[NS][4];
    #pragma unroll
    for (int s = 0; s < NS; ++s)
        #pragma unroll
        for (int bi = 0; bi < 4; ++bi)
            wf[s][bi] = *(const short8*)(wbe + ((size_t)(s * 32 + nb16 + bi) * 64 + lane) * 8);
    floatx4 bv[4];
    #pragma unroll
    for (int bi = 0; bi < 4; ++bi)
        bv[bi] = *(const floatx4*)(b + E * NOUT + n_base + bi * 16 + q * 4);

    for (int o = 0; o < c; o += 16) {
        const int L = (c - o > 16) ? 16 : (c - o);
        const int idx = (m < L) ? m : (L - 1);
        const int row = perm[boff + o + idx];
        const ushort* xr = xs + (size_t)row * PITCH + q * 8;
        floatx4 acc[4];
        #pragma unroll
        for (int bi = 0; bi < 4; ++bi) acc[bi] = bv[bi];
        #pragma unroll
        for (int s = 0; s < NS; ++s) {
            const short8 xf = *(const short8*)(xr + s * 32);
            #pragma unroll
            for (int bi = 0; bi < 4; ++bi)
                acc[bi] = __builtin_amdgcn_mfma_f32_16x16x32_bf16(wf[s][bi], xf, acc[bi], 0, 0, 0);
        }
        if (m < L) {
            float* orow = out + (size_t)(t0 + row) * NOUT + n_base + q * 4;
            #pragma unroll
            for (int bi = 0; bi < 4; ++bi)
                __builtin_nontemporal_store(acc[bi], (floatx4*)(orow + bi * 16));
        }
    }
}

// 64 consecutive tokens per block (contiguous 32 KB x read), block-local
// counting sort into per-expert groups in LDS, x staged fp32->bf16 once.
__global__ __launch_bounds__(512) void misl_main(
    const float* __restrict__ x, const int* __restrict__ feat,
    const ushort* __restrict__ wb, const float* __restrict__ b,
    float* __restrict__ out, int n) {
    __shared__ ushort xs[TPB * PITCH];
    __shared__ int perm[TPB];
    __shared__ int cnt[NEXP];
    __shared__ int base[NEXP];

    const int tid = threadIdx.x;
    const int t0 = blockIdx.x * TPB;
    const int nt = (n - t0 < TPB) ? (n - t0) : TPB;

    if (tid < NEXP) cnt[tid] = 0;

    // stage x: 8 threads per row, 16 consecutive floats each (32 KB contiguous)
    const int row = tid >> 3;
    const int colu = (tid & 7) * 16;
    float4 a0, a1, a2, a3;
    const bool stg = (row < nt);
    if (stg) {
        const float* xp = x + (size_t)(t0 + row) * MAXF + colu;
        a0 = *(const float4*)xp;
        a1 = *(const float4*)(xp + 4);
        a2 = *(const float4*)(xp + 8);
        a3 = *(const float4*)(xp + 12);
    }
    __syncthreads();                               // cnt zeroed

    int e = 0, r = 0;
    if (tid < nt) {
        e = __ffs((uint)feat[t0 + tid]) - 4;       // 8->0,16->1,32->2,64->3,128->4
        r = atomicAdd(&cnt[e], 1);
    }
    if (stg) {                                     // convert while atomics settle
        short8 v0, v1;
        v0[0] = (short)f2bf(a0.x); v0[1] = (short)f2bf(a0.y);
        v0[2] = (short)f2bf(a0.z); v0[3] = (short)f2bf(a0.w);
        v0[4] = (short)f2bf(a1.x); v0[5] = (short)f2bf(a1.y);
        v0[6] = (short)f2bf(a1.z); v0[7] = (short)f2bf(a1.w);
        v1[0] = (short)f2bf(a2.x); v1[1] = (short)f2bf(a2.y);
        v1[2] = (short)f2bf(a2.z); v1[3] = (short)f2bf(a2.w);
        v1[4] = (short)f2bf(a3.x); v1[5] = (short)f2bf(a3.y);
        v1[6] = (short)f2bf(a3.z); v1[7] = (short)f2bf(a3.w);
        *(short8*)(xs + (size_t)row * PITCH + colu)     = v0;
        *(short8*)(xs + (size_t)row * PITCH + colu + 8) = v1;
    }
    __syncthreads();                               // cnt final
    if (tid == 0) {                                // heavy experts first
        int o = 0;
        #pragma unroll
        for (int j = NEXP - 1; j >= 0; --j) { base[j] = o; o += cnt[j]; }
    }
    __syncthreads();                               // base ready
    if (tid < nt) perm[base[e] + r] = tid;
    __syncthreads();                               // perm + xs ready

    const int lane = tid & 63;
    const int n_base = (tid >> 6) * 64;            // wave -> 64-col slice
    const int c0 = cnt[0], c1 = cnt[1], c2 = cnt[2], c3 = cnt[3], c4 = cnt[4];
    const int b0 = base[0], b1 = base[1], b2 = base[2], b3 = base[3], b4 = base[4];

    if (c4) run_expert<4>(xs, perm, wb, b, out, t0, b4, c4, lane, n_base);
    if (c3) run_expert<3>(xs, perm, wb, b, out, t0, b3, c3, lane, n_base);
    if (c2) run_expert<2>(xs, perm, wb, b, out, t0, b2, c2, lane, n_base);
    if (c1) run_expert<1>(xs, perm, wb, b, out, t0, b1, c1, lane, n_base);
    if (c0) run_expert<0>(xs, perm, wb, b, out, t0, b0, c0, lane, n_base);
}

extern "C" void kernel_launch(void* const* d_in, const int* in_sizes, int n_in,
                              void* d_out, int out_size, void* d_ws, size_t ws_size,
                              hipStream_t stream) {
    const float* x    = (const float*)d_in[0];
    const int*   feat = (const int*)d_in[1];
    const float* w    = (const float*)d_in[2];
    const float* b    = (const float*)d_in[3];
    float* out = (float*)d_out;
    ushort* wb = (ushort*)d_ws;                    // 655 KB bf16 frag pack

    const int n = in_sizes[1];                     // tokens = 32768
    misl_pack<<<160, 256, 0, stream>>>(w, wb);
    misl_main<<<(n + TPB - 1) / TPB, 512, 0, stream>>>(x, feat, wb, b, out, n);
}

// Round 7
// 94.274 us; speedup vs baseline: 1.0323x; 1.0323x over previous
//
#include <hip/hip_runtime.h>

#define NEXP 5
#define MAXF 128
#define NOUT 512
#define TPB  64
#define PITCH 136   // ushorts per LDS x-row (272 B stride)
#define PACKN (NEXP * 4 * 32 * 64)   // 40960 frag-lane items

typedef __attribute__((ext_vector_type(8))) short short8;
typedef __attribute__((ext_vector_type(4))) float floatx4;

__device__ __forceinline__ ushort f2bf(float f) {   // RNE fp32->bf16
    uint u = __float_as_uint(f);
    u += 0x7FFF + ((u >> 16) & 1);
    return (ushort)(u >> 16);
}

// wb bf16 [5][4][32][64][8]: frag order, idx = ((e*4+s)*32 + nb16)*64 + lane,
// elem j at k = s*32 + (lane>>4)*8 + j, n = nb16*16 + (lane&15); zero past K.
__global__ __launch_bounds__(512) void misl_pack(
    const float* __restrict__ w, ushort* __restrict__ wb) {
    const int idx = blockIdx.x * 512 + threadIdx.x;   // 80 blocks
    if (idx < PACKN) {
        const int lane = idx & 63, nb16 = (idx >> 6) & 31;
        const int s = (idx >> 11) & 3, e = idx >> 13;
        const int ncol = nb16 * 16 + (lane & 15);
        const int k0 = s * 32 + (lane >> 4) * 8;
        const int K = 8 << e;
        const float* wr = w + ((size_t)e * NOUT + ncol) * MAXF + k0;
        short8 v;
        #pragma unroll
        for (int j = 0; j < 8; ++j)
            v[j] = (short)((k0 + j < K) ? f2bf(wr[j]) : (ushort)0);
        *(short8*)(wb + (size_t)idx * 8) = v;
    }
}

// One expert's tokens: B-frags + bias hoisted per wave from prepacked bf16 wb
// (16B vector loads), <=4 ragged 16-token groups through 16x16x32 MFMA.
// Layouts identical to the R3-verified kernel (non-swapped).
template <int E>
__device__ __forceinline__ void run_expert(
    const ushort* __restrict__ xs, const int* __restrict__ perm,
    const ushort* __restrict__ wb, const float* __restrict__ b,
    float* __restrict__ out, int t0, int boff, int c, int lane, int n_base) {
    constexpr int NS = (E == 4) ? 4 : (E == 3) ? 2 : 1;
    const int m = lane & 15, q = lane >> 4;
    const int nb16 = n_base >> 4;
    const ushort* wbe = wb + (size_t)E * 4 * 32 * 64 * 8;

    short8 bf[NS][4];
    #pragma unroll
    for (int s = 0; s < NS; ++s)
        #pragma unroll
        for (int bi = 0; bi < 4; ++bi)
            bf[s][bi] = *(const short8*)(wbe + ((size_t)(s * 32 + nb16 + bi) * 64 + lane) * 8);
    float bv[4];
    #pragma unroll
    for (int bi = 0; bi < 4; ++bi) bv[bi] = b[E * NOUT + n_base + bi * 16 + m];

    for (int o = 0; o < c; o += 16) {
        const int L = (c - o > 16) ? 16 : (c - o);
        const int idx = (m < L) ? m : (L - 1);
        const int row = perm[boff + o + idx];
        const ushort* xr = xs + (size_t)row * PITCH + q * 8;
        floatx4 acc[4];
        #pragma unroll
        for (int bi = 0; bi < 4; ++bi)
            acc[bi] = floatx4{bv[bi], bv[bi], bv[bi], bv[bi]};
        #pragma unroll
        for (int s = 0; s < NS; ++s) {
            const short8 af = *(const short8*)(xr + s * 32);
            #pragma unroll
            for (int bi = 0; bi < 4; ++bi)
                acc[bi] = __builtin_amdgcn_mfma_f32_16x16x32_bf16(af, bf[s][bi], acc[bi], 0, 0, 0);
        }
        #pragma unroll
        for (int r = 0; r < 4; ++r) {
            const int mi = q * 4 + r;
            if (mi < L) {
                const int tr = perm[boff + o + mi];      // LDS broadcast
                float* orow = out + (size_t)(t0 + tr) * NOUT + n_base + m;
                #pragma unroll
                for (int bi = 0; bi < 4; ++bi) orow[bi * 16] = acc[bi][r];
            }
        }
    }
}

// 64 consecutive tokens per block (contiguous 32 KB x read), block-local
// counting sort into per-expert groups in LDS, x staged fp32->bf16 once.
// Prologue trimmed: feat load issued at kernel entry (overlaps x loads);
// prefix bases computed redundantly per-thread (one barrier removed).
__global__ __launch_bounds__(512) void misl_main(
    const float* __restrict__ x, const int* __restrict__ feat,
    const ushort* __restrict__ wb, const float* __restrict__ b,
    float* __restrict__ out, int n) {
    __shared__ ushort xs[TPB * PITCH];
    __shared__ int perm[TPB];
    __shared__ int cnt[NEXP];

    const int tid = threadIdx.x;
    const int t0 = blockIdx.x * TPB;
    const int nt = (n - t0 < TPB) ? (n - t0) : TPB;

    int fv = 0;
    if (tid < nt) fv = feat[t0 + tid];             // issue early, use after barrier

    // stage x: 8 threads per row, 16 consecutive floats each (32 KB contiguous)
    const int row = tid >> 3;
    const int colu = (tid & 7) * 16;
    float4 a0, a1, a2, a3;
    const bool stg = (row < nt);
    if (stg) {
        const float* xp = x + (size_t)(t0 + row) * MAXF + colu;
        a0 = *(const float4*)xp;
        a1 = *(const float4*)(xp + 4);
        a2 = *(const float4*)(xp + 8);
        a3 = *(const float4*)(xp + 12);
    }
    if (tid < NEXP) cnt[tid] = 0;
    __syncthreads();                               // cnt zeroed

    int e = 0, r = 0;
    if (tid < nt) {
        e = __ffs((uint)fv) - 4;                   // 8->0,16->1,32->2,64->3,128->4
        r = atomicAdd(&cnt[e], 1);
    }
    if (stg) {                                     // convert while atomics settle
        short8 v0, v1;
        v0[0] = (short)f2bf(a0.x); v0[1] = (short)f2bf(a0.y);
        v0[2] = (short)f2bf(a0.z); v0[3] = (short)f2bf(a0.w);
        v0[4] = (short)f2bf(a1.x); v0[5] = (short)f2bf(a1.y);
        v0[6] = (short)f2bf(a1.z); v0[7] = (short)f2bf(a1.w);
        v1[0] = (short)f2bf(a2.x); v1[1] = (short)f2bf(a2.y);
        v1[2] = (short)f2bf(a2.z); v1[3] = (short)f2bf(a2.w);
        v1[4] = (short)f2bf(a3.x); v1[5] = (short)f2bf(a3.y);
        v1[6] = (short)f2bf(a3.z); v1[7] = (short)f2bf(a3.w);
        *(short8*)(xs + (size_t)row * PITCH + colu)     = v0;
        *(short8*)(xs + (size_t)row * PITCH + colu + 8) = v1;
    }
    __syncthreads();                               // cnt final

    // heavy experts first; every thread computes the 5-entry prefix locally
    const int c0 = cnt[0], c1 = cnt[1], c2 = cnt[2], c3 = cnt[3], c4 = cnt[4];
    const int b4 = 0, b3 = c4, b2 = b3 + c3, b1 = b2 + c2, b0 = b1 + c1;
    if (tid < nt) {
        const int mb = (e == 4) ? b4 : (e == 3) ? b3 : (e == 2) ? b2
                     : (e == 1) ? b1 : b0;
        perm[mb + r] = tid;
    }
    __syncthreads();                               // perm + xs ready

    const int lane = tid & 63;
    const int n_base = (tid >> 6) * 64;            // wave -> 64-col slice

    if (c4) run_expert<4>(xs, perm, wb, b, out, t0, b4, c4, lane, n_base);
    if (c3) run_expert<3>(xs, perm, wb, b, out, t0, b3, c3, lane, n_base);
    if (c2) run_expert<2>(xs, perm, wb, b, out, t0, b2, c2, lane, n_base);
    if (c1) run_expert<1>(xs, perm, wb, b, out, t0, b1, c1, lane, n_base);
    if (c0) run_expert<0>(xs, perm, wb, b, out, t0, b0, c0, lane, n_base);
}

extern "C" void kernel_launch(void* const* d_in, const int* in_sizes, int n_in,
                              void* d_out, int out_size, void* d_ws, size_t ws_size,
                              hipStream_t stream) {
    const float* x    = (const float*)d_in[0];
    const int*   feat = (const int*)d_in[1];
    const float* w    = (const float*)d_in[2];
    const float* b    = (const float*)d_in[3];
    float* out = (float*)d_out;
    ushort* wb = (ushort*)d_ws;                    // 655 KB bf16 frag pack

    const int n = in_sizes[1];                     // tokens = 32768
    misl_pack<<<(PACKN + 511) / 512, 512, 0, stream>>>(w, wb);
    misl_main<<<(n + TPB - 1) / TPB, 512, 0, stream>>>(x, feat, wb, b, out, n);
}